// Round 12
// baseline (63.473 us; speedup 1.0000x reference)
//
#include <hip/hip_runtime.h>
#include <hip/hip_bf16.h>
#include <stdint.h>

// Grouped linear: y[z] = coeff * x[z] @ W[idx[z]], idx sorted.
// C=8, U=V=512, Z=32768, fp32 in/out, bf16 MFMA compute.
//
// R12 = R6 schedule (counted-vmcnt raw barriers, A reg->cvt->ds_write depth-2,
// B gload_lds dbuf) with: (1) 4 blocks/CU (32 KB LDS, launch_bounds(256,4));
// (2) compiler-native bf16 cvt (v_cvt_pk_bf16_f32); (3) lane-linear A
// ds_writes (zero bank conflicts).

#define Cg 8
#define Ud 512
#define Vd 512
#define Zd 32768

#define BM 128
#define BN 128
#define BK 32
#define KT 16

#define TILE_US 4096             // 128 x 32 bf16 = 8 KiB
#define NBN 4
#define NBM_MAX 263              // sum ceil(cnt_g/128) <= 256+7
#define GRID_GEMM (NBM_MAX * NBN)    // 1052

#define WSW_US (Cg * NBN * KT * TILE_US)     // 4 MiB of bf16
#define WS_NEEDED ((size_t)WSW_US * 2 + 64)

typedef __attribute__((ext_vector_type(8))) short bf16x8;
typedef __attribute__((ext_vector_type(4))) float f32x4;
typedef __attribute__((ext_vector_type(4))) unsigned short us4;
typedef __attribute__((ext_vector_type(4))) float float4v;
typedef __attribute__((ext_vector_type(4))) unsigned int u32x4;

typedef __attribute__((address_space(3))) unsigned int lds_uint;
typedef const __attribute__((address_space(1))) unsigned int gbl_uint;

__device__ __forceinline__ unsigned int pk2(float lo, float hi) {
    // native casts -> compiler emits v_cvt_pk_bf16_f32 (RNE)
    unsigned short l = __bfloat16_as_ushort(__float2bfloat16(lo));
    unsigned short h = __bfloat16_as_ushort(__float2bfloat16(hi));
    return (unsigned int)l | ((unsigned int)h << 16);
}

// Subtile layout within one [128 r][32 k] tile (ushort offset):
//   (r>>4)*512 + (k>>3)*128 + (r&15)*8 + (k&7)
// Frag read (lane l): byte = rt*1024 + l4*256 + l15*16 -> contiguous 1 KiB
// per frag across the wave: conflict-free ds_read_b128 (R2/R6-verified).
// A-stage task map (lane-linear writes): thread t handles
//   rows rA = (t>>6)*16 + (t&15) and rA+64, k-offset k0 = ((t>>4)&3)*8;
//   writes land at us 8t and 8t+2048 -> ds_write_b128 perfectly linear.

// ---------------- w converter (+ group starts) ----------------

__global__ __launch_bounds__(256)
void convert_w(const float* __restrict__ w, const int* __restrict__ idx,
               unsigned short* __restrict__ wsw, int* __restrict__ starts)
{
    const int t = blockIdx.x * 256 + threadIdx.x;    // 524288 tasks
    const int g   = t >> 16;
    const int rem = t & 65535;
    const int u0  = (rem >> 9) << 2;                 // 4 k-rows
    const int v   = rem & 511;
    const float* src = w + ((size_t)g << 18) + (size_t)u0 * Vd + v;
    us4 p;
    p[0] = (unsigned short)__bfloat16_as_ushort(__float2bfloat16(src[0]));
    p[1] = (unsigned short)__bfloat16_as_ushort(__float2bfloat16(src[Vd]));
    p[2] = (unsigned short)__bfloat16_as_ushort(__float2bfloat16(src[2 * Vd]));
    p[3] = (unsigned short)__bfloat16_as_ushort(__float2bfloat16(src[3 * Vd]));
    const int r = v & 127, k = u0 & 31;
    const int tile = (g * NBN + (v >> 7)) * KT + (u0 >> 5);
    const int off  = tile * TILE_US
                   + ((r >> 4) << 9) + ((k >> 3) << 7) + ((r & 15) << 3) + (k & 7);
    *(us4*)(wsw + off) = p;

    if (blockIdx.x == 0 && threadIdx.x < 9) {
        const int gq = threadIdx.x;
        int lo = 0;
        if (gq >= 8) lo = Zd;
        else {
            int hi = Zd;
            while (lo < hi) { int mid = (lo + hi) >> 1;
                              if (idx[mid] < gq) lo = mid + 1; else hi = mid; }
        }
        starts[gq] = lo;
    }
}

// ---------------- GEMM ----------------

#define LDA(KTV, A0, A1, A2, A3) do {                                         \
    A0 = *(const float4v*)(ax0 + (KTV) * BK);                                 \
    A1 = *(const float4v*)(ax0 + (KTV) * BK + 4);                             \
    A2 = *(const float4v*)(ax1 + (KTV) * BK);                                 \
    A3 = *(const float4v*)(ax1 + (KTV) * BK + 4); } while (0)

#define CVW(BUF, A0, A1, A2, A3) do {                                         \
    u32x4 w1_, w2_;                                                           \
    w1_[0] = pk2(A0[0], A0[1]); w1_[1] = pk2(A0[2], A0[3]);                   \
    w1_[2] = pk2(A1[0], A1[1]); w1_[3] = pk2(A1[2], A1[3]);                   \
    w2_[0] = pk2(A2[0], A2[1]); w2_[1] = pk2(A2[2], A2[3]);                   \
    w2_[2] = pk2(A3[0], A3[1]); w2_[3] = pk2(A3[2], A3[3]);                   \
    *(u32x4*)(&BUF[aw])        = w1_;                                         \
    *(u32x4*)(&BUF[aw + 2048]) = w2_; } while (0)

#define GLB(KTV, BUF) do {                                                    \
    const unsigned short* s_ = wB + (size_t)(KTV) * TILE_US;                  \
    __builtin_amdgcn_global_load_lds((gbl_uint*)(s_ + bo),                    \
                                     (lds_uint*)(&BUF[bo]), 16, 0, 0);        \
    __builtin_amdgcn_global_load_lds((gbl_uint*)(s_ + bo + 2048),             \
                                     (lds_uint*)(&BUF[bo + 2048]), 16, 0, 0); \
  } while (0)

#define CMP(ABUF, BBUF) do {                                                  \
    bf16x8 a_[4], b_[4];                                                      \
    _Pragma("unroll")                                                         \
    for (int mi_ = 0; mi_ < 4; ++mi_)                                         \
        a_[mi_] = *(const bf16x8*)(&ABUF[((wm4 + mi_) << 9) + fr]);           \
    _Pragma("unroll")                                                         \
    for (int ni_ = 0; ni_ < 4; ++ni_)                                         \
        b_[ni_] = *(const bf16x8*)(&BBUF[((wn4 + ni_) << 9) + fr]);           \
    _Pragma("unroll")                                                         \
    for (int mi_ = 0; mi_ < 4; ++mi_)                                         \
        _Pragma("unroll")                                                     \
        for (int ni_ = 0; ni_ < 4; ++ni_)                                     \
            acc[mi_][ni_] = __builtin_amdgcn_mfma_f32_16x16x32_bf16(          \
                a_[mi_], b_[ni_], acc[mi_][ni_], 0, 0, 0);                    \
  } while (0)

#define WAITBAR(N) do {                                                       \
    asm volatile("s_waitcnt vmcnt(" #N ") lgkmcnt(0)" ::: "memory");          \
    __builtin_amdgcn_s_barrier(); } while (0)

#define SBAR() __builtin_amdgcn_sched_barrier(0)

__global__ __launch_bounds__(256, 4)
void sgl_gemm(const float* __restrict__ x,
              const unsigned short* __restrict__ wsw,
              const int* __restrict__ starts,
              const float* __restrict__ coeff,
              float* __restrict__ y)
{
    __shared__ unsigned short As[2][TILE_US];
    __shared__ unsigned short Bs[2][TILE_US];    // 32 KiB -> 4 blocks/CU

    const int tid = threadIdx.x, lane = tid & 63, wave = tid >> 6;
    const int l15 = lane & 15, l4 = lane >> 4;

    // bijective XCD swizzle (m204): nwg=1052, q=131, r=4; consecutive wk
    // share bmp -> the 4 bn-blocks of one x-panel land on one XCD (L2 reuse).
    const int bid = blockIdx.x;
    const int xcd = bid & 7, io = bid >> 3;
    const int wk  = (xcd < 4) ? xcd * 132 + io : 528 + (xcd - 4) * 131 + io;
    const int bmp = wk >> 2, bn = wk & 3;

    // locate group for this padded row-block
    int s[9];
#pragma unroll
    for (int i = 0; i < 9; ++i) s[i] = starts[i];
    int g = -1, lblk = 0, ab = 0;
#pragma unroll
    for (int gg = 0; gg < 8; ++gg) {
        const int c  = s[gg + 1] - s[gg];
        const int nb = (c + BM - 1) >> 7;
        if (g < 0 && bmp < ab + nb) { g = gg; lblk = bmp - ab; }
        ab += nb;
    }
    if (g < 0) return;
    const int start = s[g];
    const int cnt   = s[g + 1] - s[g];
    const int j0    = lblk << 7;

    // A task map (lane-linear LDS writes): rows rA, rA+64; k0 = ((t>>4)&3)*8
    const int rA = ((tid >> 6) << 4) + (tid & 15);
    const int k0 = ((tid >> 4) & 3) << 3;
    const int rc0 = (j0 + rA < cnt) ? (j0 + rA) : (cnt - 1);
    const int rc1 = (j0 + rA + 64 < cnt) ? (j0 + rA + 64) : (cnt - 1);
    const float* ax0 = x + (size_t)(start + rc0) * Ud + k0;
    const float* ax1 = x + (size_t)(start + rc1) * Ud + k0;
    const int aw = tid * 8;                  // us; writes at aw, aw+2048

    // B: linear gload_lds from pre-tiled ws (8 KiB tile, 2 x 16B per thread)
    const unsigned short* wB = wsw + (size_t)((g * NBN + bn) * KT) * TILE_US;
    const int bo = tid * 8;

    const int wm4 = (wave >> 1) << 2;
    const int wn4 = (wave & 1) << 2;
    const int fr  = (l4 << 7) + (l15 << 3);

    f32x4 acc[4][4];
#pragma unroll
    for (int mi = 0; mi < 4; ++mi)
#pragma unroll
        for (int ni = 0; ni < 4; ++ni)
            acc[mi][ni] = f32x4{0.f, 0.f, 0.f, 0.f};

    float4v e0, e1, e2, e3, o0, o1, o2, o3;

    // prologue: A(0)->e, B(0), A(1)->o ; cvt A(0); barrier leaves A(1) flying
    LDA(0, e0, e1, e2, e3);
    SBAR();
    GLB(0, Bs[0]);
    SBAR();
    LDA(1, o0, o1, o2, o3);
    SBAR();
    CVW(As[0], e0, e1, e2, e3);
    WAITBAR(4);

    // steady state: iter kt stages B(kt+1)+A(kt+2), cvts A(kt+1), computes kt.
    // Barrier waits vmcnt(4): B(kt+1) done, A(kt+2) reg-loads stay in flight.
#pragma unroll
    for (int kt = 0; kt < 14; ++kt) {
        if ((kt & 1) == 0) {
            GLB(kt + 1, Bs[1]);
            SBAR();
            LDA(kt + 2, e0, e1, e2, e3);
            SBAR();
            CVW(As[1], o0, o1, o2, o3);
            CMP(As[0], Bs[0]);
        } else {
            GLB(kt + 1, Bs[0]);
            SBAR();
            LDA(kt + 2, o0, o1, o2, o3);
            SBAR();
            CVW(As[0], e0, e1, e2, e3);
            CMP(As[1], Bs[1]);
        }
        WAITBAR(4);
    }
    // kt = 14 (A(15) is in o; no more prefetch)
    GLB(15, Bs[1]);
    SBAR();
    CVW(As[1], o0, o1, o2, o3);
    CMP(As[0], Bs[0]);
    WAITBAR(0);
    // kt = 15
    CMP(As[1], Bs[1]);

    // epilogue: C/D col=lane&15, row=(lane>>4)*4+q; mask padded rows
    const float cf = coeff[0];
    const bool full = (j0 + BM) <= cnt;
#pragma unroll
    for (int mi = 0; mi < 4; ++mi) {
        const int rb = ((wave >> 1) << 6) + mi * 16 + l4 * 4;
#pragma unroll
        for (int ni = 0; ni < 4; ++ni) {
            const int c = bn * BN + ((wave & 1) << 6) + ni * 16 + l15;
#pragma unroll
            for (int q = 0; q < 4; ++q) {
                if (full || (j0 + rb + q) < cnt)
                    y[(size_t)(start + j0 + rb + q) * Vd + c] = acc[mi][ni][q] * cf;
            }
        }
    }
}

// ---------------- safety-net fallback (ws too small; not expected) --------

__global__ __launch_bounds__(256)
void sgl_naive(const float* __restrict__ w, const float* __restrict__ x,
               const int* __restrict__ idx, const float* __restrict__ coeff,
               float* __restrict__ y)
{
    __shared__ float xs[Ud];
    const int z = blockIdx.x;
    const int g = idx[z];
    for (int u = threadIdx.x; u < Ud; u += 256) xs[u] = x[(size_t)z * Ud + u];
    __syncthreads();
    const float* Wg = w + (size_t)g * (Ud * Vd);
    const float cf = coeff[0];
    for (int v = threadIdx.x; v < Vd; v += 256) {
        float acc = 0.f;
        for (int u = 0; u < Ud; ++u) acc += xs[u] * Wg[(size_t)u * Vd + v];
        y[(size_t)z * Vd + v] = acc * cf;
    }
}

extern "C" void kernel_launch(void* const* d_in, const int* in_sizes, int n_in,
                              void* d_out, int out_size, void* d_ws, size_t ws_size,
                              hipStream_t stream) {
    const float* w     = (const float*)d_in[0];
    const float* x     = (const float*)d_in[1];
    const int*   idx   = (const int*)d_in[2];
    const float* coeff = (const float*)d_in[3];
    float* y = (float*)d_out;

    if (ws_size >= WS_NEEDED) {
        unsigned short* wsw = (unsigned short*)d_ws;
        int* starts = (int*)((char*)d_ws + (size_t)WSW_US * 2);
        hipLaunchKernelGGL(convert_w, dim3(2048), dim3(256), 0, stream,
                           w, idx, wsw, starts);
        hipLaunchKernelGGL(sgl_gemm, dim3(GRID_GEMM), dim3(256), 0, stream,
                           x, wsw, starts, coeff, y);
    } else {
        hipLaunchKernelGGL(sgl_naive, dim3(Zd), dim3(256), 0, stream,
                           w, x, idx, coeff, y);
    }
}

// Round 13
// 54.459 us; speedup vs baseline: 1.1655x; 1.1655x over previous
//
#include <hip/hip_runtime.h>
#include <hip/hip_bf16.h>
#include <stdint.h>

// Grouped linear: y[z] = coeff * x[z] @ W[idx[z]], idx sorted.
// C=8, U=V=512, Z=32768, fp32 in/out, bf16 MFMA compute.
//
// R13: x-read-ONCE design. Block = 32 rows x 512 cols (NBN=1 -> zero x
// re-reads; L3-fabric traffic ~470->~170 MB). A: full-K 32-row panel staged
// once to LDS (32 KB, lane-linear, conflict-free), ONE barrier, then a
// barrier-free K-loop. B: per-wave 64-col panel loaded DIRECT to registers
// from L2-resident pre-tiled bf16 wsw (1KB wave-contiguous frags), ring-3.
// 8 waves x (32x64), acc[2][4], target <=128 VGPR -> 16 waves/CU.

#define Cg 8
#define Ud 512
#define Vd 512
#define Zd 32768

#define KT 16                    // K-steps of 32
#define BROW 32
#define NBM_MAX 1031             // sum ceil(cnt_g/32) <= 1024+7
#define GRID_GEMM NBM_MAX

#define WSW_US (Cg * 8 * KT * 4 * 512)   // [g][vb8][kt16][ct4][512us] = 4 MiB
#define WS_NEEDED ((size_t)WSW_US * 2 + 64)

typedef __attribute__((ext_vector_type(8))) short bf16x8;
typedef __attribute__((ext_vector_type(4))) float f32x4;
typedef __attribute__((ext_vector_type(4))) unsigned short us4;
typedef __attribute__((ext_vector_type(4))) float float4v;
typedef __attribute__((ext_vector_type(4))) unsigned int u32x4;

__device__ __forceinline__ unsigned int pk2(float lo, float hi) {
    unsigned short l = __bfloat16_as_ushort(__float2bfloat16(lo));
    unsigned short h = __bfloat16_as_ushort(__float2bfloat16(hi));
    return (unsigned int)l | ((unsigned int)h << 16);
}

// ---------------- w converter (+ group starts) ----------------
// wsw: [g][vb(8 col-blocks of 64)][kt(16)][ct(4 col-subtiles of 16)][512 us]
// subtile (c 0..15, k 0..31): (k>>3)*128 + c*8 + (k&7); frag read (lane l):
// us = l4*128 + l15*8 -> 1 KB wave-contiguous.

__global__ __launch_bounds__(256)
void convert_w(const float* __restrict__ w, const int* __restrict__ idx,
               unsigned short* __restrict__ wsw, int* __restrict__ starts)
{
    const int t = blockIdx.x * 256 + threadIdx.x;    // 524288 tasks
    const int g   = t >> 16;
    const int rem = t & 65535;
    const int u0  = (rem >> 9) << 2;                 // 4 k-rows
    const int v   = rem & 511;
    const float* src = w + ((size_t)g << 18) + (size_t)u0 * Vd + v;
    us4 p;
    p[0] = (unsigned short)__bfloat16_as_ushort(__float2bfloat16(src[0]));
    p[1] = (unsigned short)__bfloat16_as_ushort(__float2bfloat16(src[Vd]));
    p[2] = (unsigned short)__bfloat16_as_ushort(__float2bfloat16(src[2 * Vd]));
    p[3] = (unsigned short)__bfloat16_as_ushort(__float2bfloat16(src[3 * Vd]));
    const int vb = v >> 6, ct = (v >> 4) & 3, c = v & 15;
    const int kt = u0 >> 5;
    const int off = ((((g * 8 + vb) * KT + kt) * 4 + ct) << 9)
                  + (((u0 & 31) >> 3) << 7) + (c << 3) + (u0 & 7);
    *(us4*)(wsw + off) = p;

    if (blockIdx.x == 0 && threadIdx.x < 9) {
        const int gq = threadIdx.x;
        int lo = 0;
        if (gq >= 8) lo = Zd;
        else {
            int hi = Zd;
            while (lo < hi) { int mid = (lo + hi) >> 1;
                              if (idx[mid] < gq) lo = mid + 1; else hi = mid; }
        }
        starts[gq] = lo;
    }
}

// ---------------- GEMM ----------------

#define LDB(KTV, R) do {                                                      \
    _Pragma("unroll")                                                         \
    for (int ni_ = 0; ni_ < 4; ++ni_)                                         \
        R[ni_] = *(const bf16x8*)(wV + ((KTV) << 11) + (ni_ << 9) + fr);      \
  } while (0)

#define CMPK(KTV, R) do {                                                     \
    bf16x8 a_[2];                                                             \
    a_[0] = *(const bf16x8*)(&As[((KTV) << 10) + fr]);                        \
    a_[1] = *(const bf16x8*)(&As[((KTV) << 10) + 512 + fr]);                  \
    _Pragma("unroll")                                                         \
    for (int mi_ = 0; mi_ < 2; ++mi_)                                         \
        _Pragma("unroll")                                                     \
        for (int ni_ = 0; ni_ < 4; ++ni_)                                     \
            acc[mi_][ni_] = __builtin_amdgcn_mfma_f32_16x16x32_bf16(          \
                a_[mi_], R[ni_], acc[mi_][ni_], 0, 0, 0);                     \
  } while (0)

__global__ __launch_bounds__(512, 4)
void sgl_gemm(const float* __restrict__ x,
              const unsigned short* __restrict__ wsw,
              const int* __restrict__ starts,
              const float* __restrict__ coeff,
              float* __restrict__ y)
{
    // A: [kt(16)][rt(2)*512 + ko(4)*128 + (r&15)*8 + (k&7)] = 16K us = 32 KiB
    __shared__ unsigned short As[KT * 1024];

    const int tid = threadIdx.x, lane = tid & 63, wave = tid >> 6;
    const int l15 = lane & 15, l4 = lane >> 4;
    const int fr  = (l4 << 7) + (l15 << 3);

    // bijective XCD swizzle (m204): nwg=1031, q=128, r=7. Consecutive wk on
    // one XCD share the same group g -> W[g] bf16 (512 KB) L2-resident.
    const int bid = blockIdx.x;
    const int xcd = bid & 7, io = bid >> 3;
    const int wk  = (xcd < 7) ? xcd * 129 + io : 903 + io;
    const int bmp = wk;

    // locate group for this padded 32-row block
    int s[9];
#pragma unroll
    for (int i = 0; i < 9; ++i) s[i] = starts[i];
    int g = -1, lblk = 0, ab = 0;
#pragma unroll
    for (int gg = 0; gg < 8; ++gg) {
        const int c  = s[gg + 1] - s[gg];
        const int nb = (c + BROW - 1) >> 5;
        if (g < 0 && bmp < ab + nb) { g = gg; lblk = bmp - ab; }
        ab += nb;
    }
    if (g < 0) return;
    const int start = s[g];
    const int cnt   = s[g + 1] - s[g];
    const int j0    = lblk << 5;

    // ---- A stage: 2048 octet-tasks over 512 threads, 4 each ----
    // task tau = t + 512j: kt = 4j + (t>>7), r = (t>>2)&31, ko = t&3.
    // Loads: 4 consecutive lanes cover 128 B of one row (full lines, x read
    // exactly once chip-wide). Writes: wave covers 1 KB contiguous LDS.
    const int sr  = (tid >> 2) & 31;
    const int sko = (tid & 3) << 3;
    const int sk4 = tid >> 7;                 // 0..3
    const int rc  = (j0 + sr < cnt) ? (j0 + sr) : (cnt - 1);
    const float* sx = x + (size_t)(start + rc) * Ud + sko;
    const int swb = ((sr >> 4) << 9) + ((sko >> 3) << 7) + ((sr & 15) << 3);

    float4v sv[4][2];
#pragma unroll
    for (int j = 0; j < 4; ++j) {
        const int kt = 4 * j + sk4;
        sv[j][0] = *(const float4v*)(sx + kt * 32);
        sv[j][1] = *(const float4v*)(sx + kt * 32 + 4);
    }

    // B ring prefetch (kt 0..2) issued before the barrier; stay in flight.
    const unsigned short* wV = wsw + ((size_t)((g * 8 + wave) * KT) << 11);
    bf16x8 B0[4], B1[4], B2[4];
    LDB(0, B0);
    LDB(1, B1);
    LDB(2, B2);

#pragma unroll
    for (int j = 0; j < 4; ++j) {
        const int kt = 4 * j + sk4;
        u32x4 pw;
        pw[0] = pk2(sv[j][0][0], sv[j][0][1]);
        pw[1] = pk2(sv[j][0][2], sv[j][0][3]);
        pw[2] = pk2(sv[j][1][0], sv[j][1][1]);
        pw[3] = pk2(sv[j][1][2], sv[j][1][3]);
        *(u32x4*)(&As[(kt << 10) + swb]) = pw;
    }

    f32x4 acc[2][4];
#pragma unroll
    for (int mi = 0; mi < 2; ++mi)
#pragma unroll
        for (int ni = 0; ni < 4; ++ni)
            acc[mi][ni] = f32x4{0.f, 0.f, 0.f, 0.f};

    asm volatile("s_waitcnt lgkmcnt(0)" ::: "memory");   // ds_writes done
    __builtin_amdgcn_s_barrier();                        // ONLY barrier

    // ---- barrier-free K-loop, ring-3 B (2 steps of L2 cover) ----
#pragma unroll
    for (int kt = 0; kt < KT; ++kt) {
        if ((kt % 3) == 0) {
            if (kt + 3 < KT) { CMPK(kt, B0); LDB(kt + 3, B0); }
            else               CMPK(kt, B0);
        } else if ((kt % 3) == 1) {
            if (kt + 3 < KT) { CMPK(kt, B1); LDB(kt + 3, B1); }
            else               CMPK(kt, B1);
        } else {
            if (kt + 3 < KT) { CMPK(kt, B2); LDB(kt + 3, B2); }
            else               CMPK(kt, B2);
        }
    }

    // epilogue: C/D col=lane&15, row=(lane>>4)*4+q; mask padded rows
    const float cf = coeff[0];
    const bool full = (j0 + BROW) <= cnt;
#pragma unroll
    for (int mi = 0; mi < 2; ++mi) {
        const int rb = mi * 16 + l4 * 4;
#pragma unroll
        for (int ni = 0; ni < 4; ++ni) {
            const int c = wave * 64 + ni * 16 + l15;
#pragma unroll
            for (int q = 0; q < 4; ++q) {
                if (full || (j0 + rb + q) < cnt)
                    y[(size_t)(start + j0 + rb + q) * Vd + c] = acc[mi][ni][q] * cf;
            }
        }
    }
}

// ---------------- safety-net fallback (ws too small; not expected) --------

__global__ __launch_bounds__(256)
void sgl_naive(const float* __restrict__ w, const float* __restrict__ x,
               const int* __restrict__ idx, const float* __restrict__ coeff,
               float* __restrict__ y)
{
    __shared__ float xs[Ud];
    const int z = blockIdx.x;
    const int g = idx[z];
    for (int u = threadIdx.x; u < Ud; u += 256) xs[u] = x[(size_t)z * Ud + u];
    __syncthreads();
    const float* Wg = w + (size_t)g * (Ud * Vd);
    const float cf = coeff[0];
    for (int v = threadIdx.x; v < Vd; v += 256) {
        float acc = 0.f;
        for (int u = 0; u < Ud; ++u) acc += xs[u] * Wg[(size_t)u * Vd + v];
        y[(size_t)z * Vd + v] = acc * cf;
    }
}

extern "C" void kernel_launch(void* const* d_in, const int* in_sizes, int n_in,
                              void* d_out, int out_size, void* d_ws, size_t ws_size,
                              hipStream_t stream) {
    const float* w     = (const float*)d_in[0];
    const float* x     = (const float*)d_in[1];
    const int*   idx   = (const int*)d_in[2];
    const float* coeff = (const float*)d_in[3];
    float* y = (float*)d_out;

    if (ws_size >= WS_NEEDED) {
        unsigned short* wsw = (unsigned short*)d_ws;
        int* starts = (int*)((char*)d_ws + (size_t)WSW_US * 2);
        hipLaunchKernelGGL(convert_w, dim3(2048), dim3(256), 0, stream,
                           w, idx, wsw, starts);
        hipLaunchKernelGGL(sgl_gemm, dim3(GRID_GEMM), dim3(512), 0, stream,
                           x, wsw, starts, coeff, y);
    } else {
        hipLaunchKernelGGL(sgl_naive, dim3(Zd), dim3(256), 0, stream,
                           w, x, idx, coeff, y);
    }
}